// Round 9
// baseline (532.907 us; speedup 1.0000x reference)
//
#include <hip/hip_runtime.h>
#include <cstdint>
#include <cstddef>

#define NN 100000
#define NE 1600000
#define NH 8
#define NC 40
#define NBKT 391            // ceil(NN / 256)
#define CHUNK 8192
#define P2BLKS ((NE + CHUNK - 1) / CHUNK)

typedef _Float16 f16;
typedef f16 f16x2 __attribute__((ext_vector_type(2)));
typedef f16 f16x4 __attribute__((ext_vector_type(4)));
typedef f16 f16x8 __attribute__((ext_vector_type(8)));

static __device__ __forceinline__ float leaky02(float x) {
  return x >= 0.f ? x : 0.2f * x;
}

// Detect whether edge arrays are int64 (odd int32 halves all zero) or int32.
__global__ void detect_kernel(const int* __restrict__ e, int* __restrict__ flag) {
  int i = blockIdx.x * blockDim.x + threadIdx.x;
  if (i < 1024) {
    if (e[2 * i + 1] != 0) atomicExch(flag, 1);
  }
}

static __device__ __forceinline__ int edge_at(const void* p, int is32, int i) {
  return is32 ? ((const int*)p)[i] : (int)((const long long*)p)[i];
}

// ------- layer-1 projection: h1 = x @ W1 (128x128), f16 out, fused att dots -
__global__ __launch_bounds__(256) void gemm1_kernel(
    const float* __restrict__ x, const float* __restrict__ W1,
    const float* __restrict__ att_src, const float* __restrict__ att_dst,
    f16* __restrict__ h1, float* __restrict__ as1, float* __restrict__ ad1) {
  __shared__ float wsm[128 * 128];   // [k][c]
  __shared__ float xs[16][136];
  for (int i = threadIdx.x; i < 128 * 32; i += 256)
    ((float4*)wsm)[i] = ((const float4*)W1)[i];
  const int r = threadIdx.x >> 4;      // row within tile (0..15)
  const int i16 = threadIdx.x & 15;    // column group
  const int ca = i16 * 4, cb = 64 + i16 * 4;
  const float4 asA = *(const float4*)(att_src + ca);
  const float4 asB = *(const float4*)(att_src + cb);
  const float4 adA = *(const float4*)(att_dst + ca);
  const float4 adB = *(const float4*)(att_dst + cb);
  const int hA = i16 >> 2, hB = 4 + (i16 >> 2);
  const int nt = (NN + 15) / 16;
  for (int tile = blockIdx.x; tile < nt; tile += gridDim.x) {
    const int row0 = tile * 16;
    __syncthreads();
    for (int t = threadIdx.x; t < 16 * 32; t += 256) {
      int rr = t >> 5, c4 = t & 31;
      int row = row0 + rr;
      float4 v = make_float4(0.f, 0.f, 0.f, 0.f);
      if (row < NN) v = ((const float4*)(x + (size_t)row * 128))[c4];
      *(float4*)&xs[rr][c4 * 4] = v;
    }
    __syncthreads();
    float4 accA = make_float4(0.f, 0.f, 0.f, 0.f);
    float4 accB = make_float4(0.f, 0.f, 0.f, 0.f);
#pragma unroll 8
    for (int k = 0; k < 128; ++k) {
      float xv = xs[r][k];
      float4 wa = *(const float4*)&wsm[k * 128 + ca];
      float4 wb = *(const float4*)&wsm[k * 128 + cb];
      accA.x += xv * wa.x; accA.y += xv * wa.y;
      accA.z += xv * wa.z; accA.w += xv * wa.w;
      accB.x += xv * wb.x; accB.y += xv * wb.y;
      accB.z += xv * wb.z; accB.w += xv * wb.w;
    }
    float psA = accA.x * asA.x + accA.y * asA.y + accA.z * asA.z + accA.w * asA.w;
    float psB = accB.x * asB.x + accB.y * asB.y + accB.z * asB.z + accB.w * asB.w;
    float pdA = accA.x * adA.x + accA.y * adA.y + accA.z * adA.z + accA.w * adA.w;
    float pdB = accB.x * adB.x + accB.y * adB.y + accB.z * adB.z + accB.w * adB.w;
    psA += __shfl_xor(psA, 1); psA += __shfl_xor(psA, 2);
    psB += __shfl_xor(psB, 1); psB += __shfl_xor(psB, 2);
    pdA += __shfl_xor(pdA, 1); pdA += __shfl_xor(pdA, 2);
    pdB += __shfl_xor(pdB, 1); pdB += __shfl_xor(pdB, 2);
    const int row = row0 + r;
    if (row < NN) {
      f16x4 oa = { (f16)accA.x, (f16)accA.y, (f16)accA.z, (f16)accA.w };
      f16x4 ob = { (f16)accB.x, (f16)accB.y, (f16)accB.z, (f16)accB.w };
      *(f16x4*)(h1 + (size_t)row * 128 + ca) = oa;
      *(f16x4*)(h1 + (size_t)row * 128 + cb) = ob;
      if ((i16 & 3) == 0) {
        as1[row * 8 + hA] = psA;
        as1[row * 8 + hB] = psB;
        ad1[row * 8 + hA] = pdA;
        ad1[row * 8 + hB] = pdB;
      }
    }
  }
}

// ---------------- CSR build: bucketed counting sort ----------------
__global__ __launch_bounds__(256) void bucketcnt_kernel(
    const void* __restrict__ dst, const int* __restrict__ flag,
    int* __restrict__ gbucket) {
  __shared__ int h[NBKT];
  const int t = threadIdx.x;
  for (int i = t; i < NBKT; i += 256) h[i] = 0;
  __syncthreads();
  const int is32 = *flag;
  int i = blockIdx.x * 256 + t;
  const int st = gridDim.x * 256;
  for (; i < NE; i += st) atomicAdd(&h[edge_at(dst, is32, i) >> 8], 1);
  __syncthreads();
  for (int b = t; b < NBKT; b += 256)
    if (h[b]) atomicAdd(&gbucket[b], h[b]);
}

__global__ __launch_bounds__(512) void bucketscan_kernel(
    const int* __restrict__ gbucket, int* __restrict__ bb,
    int* __restrict__ bcur) {
  __shared__ int wsum[8];
  const int t = threadIdx.x;
  const int lane = t & 63, w = t >> 6;
  int v = (t < NBKT) ? gbucket[t] : 0;
  int sc = v;
#pragma unroll
  for (int off = 1; off < 64; off <<= 1) {
    int o = __shfl_up(sc, off);
    if (lane >= off) sc += o;
  }
  if (lane == 63) wsum[w] = sc;
  __syncthreads();
  if (t < 8) {
    int ws = wsum[t];
#pragma unroll
    for (int off = 1; off < 8; off <<= 1) {
      int o = __shfl_up(ws, off);
      if (t >= off) ws += o;
    }
    wsum[t] = ws;
  }
  __syncthreads();
  if (w > 0) sc += wsum[w - 1];
  if (t < NBKT) {
    int ex = sc - v;
    bb[t] = ex;
    bcur[t] = ex;
  }
  if (t == NBKT - 1) bb[NBKT] = sc;   // == NE
}

__global__ __launch_bounds__(256) void partition_kernel(
    const void* __restrict__ src, const void* __restrict__ dst,
    const int* __restrict__ flag, int* __restrict__ bcur,
    unsigned int* __restrict__ bucketbuf) {
  __shared__ int h[NBKT];
  __shared__ int gb[NBKT];
  const int t = threadIdx.x;
  const int is32 = *flag;
  const int lo = blockIdx.x * CHUNK;
  const int hi = min(lo + CHUNK, NE);
  for (int i = t; i < NBKT; i += 256) h[i] = 0;
  __syncthreads();
  for (int i = lo + t; i < hi; i += 256)
    atomicAdd(&h[edge_at(dst, is32, i) >> 8], 1);
  __syncthreads();
  for (int b = t; b < NBKT; b += 256)
    gb[b] = h[b] ? atomicAdd(&bcur[b], h[b]) : 0;
  __syncthreads();
  for (int i = t; i < NBKT; i += 256) h[i] = 0;   // reuse as local cursor
  __syncthreads();
  for (int i = lo + t; i < hi; i += 256) {
    int d = edge_at(dst, is32, i);
    int b = d >> 8;
    int s = atomicAdd(&h[b], 1);
    bucketbuf[gb[b] + s] =
        ((unsigned)(d & 255) << 17) | (unsigned)edge_at(src, is32, i);
  }
}

__global__ __launch_bounds__(256) void build_kernel(
    const unsigned int* __restrict__ bucketbuf, const int* __restrict__ bb,
    int* __restrict__ rowptr, int* __restrict__ csr) {
  __shared__ int cnt[256];
  __shared__ int cur[256];
  __shared__ int wsum[4];
  const int k = blockIdx.x;
  const int t = threadIdx.x;
  const int node0 = k << 8;
  const int lo = bb[k], hi = bb[k + 1];
  cnt[t] = 0;
  __syncthreads();
  for (int i = lo + t; i < hi; i += 256)
    atomicAdd(&cnt[bucketbuf[i] >> 17], 1);
  __syncthreads();
  const int lane = t & 63, w = t >> 6;
  const int v = cnt[t];
  int sc = v;
#pragma unroll
  for (int off = 1; off < 64; off <<= 1) {
    int o = __shfl_up(sc, off);
    if (lane >= off) sc += o;
  }
  if (lane == 63) wsum[w] = sc;
  __syncthreads();
  if (t < 4) {
    int ws = wsum[t];
#pragma unroll
    for (int off = 1; off < 4; off <<= 1) {
      int o = __shfl_up(ws, off);
      if (t >= off) ws += o;
    }
    wsum[t] = ws;
  }
  __syncthreads();
  if (w > 0) sc += wsum[w - 1];
  const int ex = lo + sc - v;
  const int node = node0 + t;
  if (node < NN) rowptr[node] = ex;
  if (node == NN - 1) rowptr[NN] = NE;
  cur[t] = ex;
  __syncthreads();
  for (int i = lo + t; i < hi; i += 256) {
    unsigned e = bucketbuf[i];
    int pos = atomicAdd(&cur[e >> 17], 1);
    csr[pos] = (int)(e & 0x1FFFF);
  }
}

// ---- prep: W2e[128][64]: cols 0..39 = W2, col 40 = W2@as2, col 41 = W2@ad2 -
__global__ __launch_bounds__(256) void wprep_kernel(
    const float* __restrict__ W2, const float* __restrict__ as2v,
    const float* __restrict__ ad2v, float* __restrict__ W2e) {
  for (int i = threadIdx.x; i < 128 * 64; i += 256) {
    const int k = i >> 6, c = i & 63;
    float v = 0.f;
    if (c < 40) {
      v = W2[k * 40 + c];
    } else if (c == 40 || c == 41) {
      const float* a = (c == 40) ? as2v : ad2v;
      float s = 0.f;
#pragma unroll 8
      for (int j = 0; j < 40; ++j) s += W2[k * 40 + j] * a[j];
      v = s;
    }
    W2e[i] = v;
  }
}

// --- layer-1 aggregate + softmax + ELU; g1 (f32) ---
// stats: lane = j*8+hd, first 4 batches cached in regs; PV: lane = q*16+part.
__global__ __launch_bounds__(256) void agg1_kernel(
    const f16* __restrict__ h1, const float* __restrict__ as1,
    const float* __restrict__ ad1, const int* __restrict__ rowptr,
    const int* __restrict__ csr, float* __restrict__ g1) {
  const int wid = (blockIdx.x * 256 + threadIdx.x) >> 6;
  const int lane = threadIdx.x & 63;
  if (wid >= NN) return;
  const int lo = rowptr[wid], hi = rowptr[wid + 1];
  const int deg = hi - lo;
  const int j = lane >> 3, hd = lane & 7;
  const float advv = ad1[wid * 8 + hd];
  // cached stats for first 32 edges (covers ~all of Poisson-16)
  float lk0 = -3.4e38f, lk1 = -3.4e38f, lk2 = -3.4e38f, lk3 = -3.4e38f;
  int s0 = 0, s1 = 0, s2 = 0, s3 = 0;
  if (j < deg)      { s0 = csr[lo + j];      lk0 = leaky02(as1[(size_t)s0 * 8 + hd] + advv); }
  if (8 + j < deg)  { s1 = csr[lo + 8 + j];  lk1 = leaky02(as1[(size_t)s1 * 8 + hd] + advv); }
  if (16 + j < deg) { s2 = csr[lo + 16 + j]; lk2 = leaky02(as1[(size_t)s2 * 8 + hd] + advv); }
  if (24 + j < deg) { s3 = csr[lo + 24 + j]; lk3 = leaky02(as1[(size_t)s3 * 8 + hd] + advv); }
  float m = fmaxf(fmaxf(lk0, lk1), fmaxf(lk2, lk3));
  for (int base = 32; base < deg; base += 8) {   // rare tail
    int e = base + j;
    float xv = (e < deg) ? leaky02(as1[(size_t)csr[lo + e] * 8 + hd] + advv)
                         : -3.4e38f;
    m = fmaxf(m, xv);
  }
  m = fmaxf(m, __shfl_xor(m, 8));
  m = fmaxf(m, __shfl_xor(m, 16));
  m = fmaxf(m, __shfl_xor(m, 32));
  const int q = lane >> 4;          // PV edge sub-slot (0..3)
  const int part = lane & 15;       // 8-feature block
  float sum = 0.f;
  float acc[8];
#pragma unroll
  for (int i = 0; i < 8; ++i) acc[i] = 0.f;
  for (int base = 0; base < deg; base += 8) {
    int e = base + j;
    float p = 0.f;
    int s = 0;
    if (base == 0)       { s = s0; if (e < deg) p = __expf(lk0 - m); }
    else if (base == 8)  { s = s1; if (e < deg) p = __expf(lk1 - m); }
    else if (base == 16) { s = s2; if (e < deg) p = __expf(lk2 - m); }
    else if (base == 24) { s = s3; if (e < deg) p = __expf(lk3 - m); }
    else if (e < deg) {
      s = csr[lo + e];
      p = __expf(leaky02(as1[(size_t)s * 8 + hd] + advv) - m);
    }
    sum += p;
    int sja = __shfl(s, q * 8);
    float pja = __shfl(p, q * 8 + (part >> 1));
    int sjb = __shfl(s, (4 + q) * 8);
    float pjb = __shfl(p, (4 + q) * 8 + (part >> 1));
    f16x8 hva = *(const f16x8*)(h1 + (size_t)sja * 128 + part * 8);
    f16x8 hvb = *(const f16x8*)(h1 + (size_t)sjb * 128 + part * 8);
#pragma unroll
    for (int i = 0; i < 8; ++i) acc[i] += pja * (float)hva[i];
#pragma unroll
    for (int i = 0; i < 8; ++i) acc[i] += pjb * (float)hvb[i];
  }
  sum += __shfl_xor(sum, 8);
  sum += __shfl_xor(sum, 16);
  sum += __shfl_xor(sum, 32);
#pragma unroll
  for (int i = 0; i < 8; ++i) {
    acc[i] += __shfl_xor(acc[i], 16);
    acc[i] += __shfl_xor(acc[i], 32);
  }
  float sden = __shfl(sum, part >> 1);
  float inv = 1.f / fmaxf(sden, 1e-16f);
  if (lane < 16) {
    float o[8];
#pragma unroll
    for (int i = 0; i < 8; ++i) {
      float v = acc[i] * inv;
      o[i] = v > 0.f ? v : (__expf(v) - 1.f);
    }
    float4 v0 = { o[0], o[1], o[2], o[3] };
    float4 v1 = { o[4], o[5], o[6], o[7] };
    *(float4*)(g1 + (size_t)wid * 128 + part * 8) = v0;
    *(float4*)(g1 + (size_t)wid * 128 + part * 8 + 4) = v1;
  }
}

// ------- layer-2 projection: h2p = g1 @ W2e (padded 64 cols incl logits) ----
// wave = 8 rows, 4 rows share each coalesced W2e load; g1 rows via s_load.
__global__ __launch_bounds__(256) void gemm2_kernel(
    const float* __restrict__ g1, const float* __restrict__ W2e,
    f16* __restrict__ h2p, float* __restrict__ as2, float* __restrict__ ad2) {
  const int lane = threadIdx.x & 63;
  const int wid = (blockIdx.x * 256 + threadIdx.x) >> 6;   // 0..12499
  const int row0 = wid * 8;
#pragma unroll
  for (int rb = 0; rb < 8; rb += 4) {
    const int r0 = row0 + rb;
    const int ri = __builtin_amdgcn_readfirstlane(r0);
    const float* __restrict__ rp0 = g1 + (size_t)ri * 128;
    const float* __restrict__ rp1 = rp0 + 128;
    const float* __restrict__ rp2 = rp0 + 256;
    const float* __restrict__ rp3 = rp0 + 384;
    float a0 = 0.f, a1 = 0.f, a2 = 0.f, a3 = 0.f;
#pragma unroll
    for (int k = 0; k < 128; ++k) {
      float wv = W2e[k * 64 + lane];
      a0 += rp0[k] * wv;
      a1 += rp1[k] * wv;
      a2 += rp2[k] * wv;
      a3 += rp3[k] * wv;
    }
    const f16 z = (f16)0.f;
    h2p[(size_t)(r0 + 0) * 64 + lane] = (lane < 40) ? (f16)a0 : z;
    h2p[(size_t)(r0 + 1) * 64 + lane] = (lane < 40) ? (f16)a1 : z;
    h2p[(size_t)(r0 + 2) * 64 + lane] = (lane < 40) ? (f16)a2 : z;
    h2p[(size_t)(r0 + 3) * 64 + lane] = (lane < 40) ? (f16)a3 : z;
    if (lane == 40) {
      as2[r0 + 0] = a0; as2[r0 + 1] = a1; as2[r0 + 2] = a2; as2[r0 + 3] = a3;
    } else if (lane == 41) {
      ad2[r0 + 0] = a0; ad2[r0 + 1] = a1; ad2[r0 + 2] = a2; ad2[r0 + 3] = a3;
    }
  }
}

// ---------------- layer-2 aggregate + softmax -> d_out ----------------
// stats: lane = edge offset (first 64 cached); PV: lane = j*8+part8, f16x8.
__global__ __launch_bounds__(256) void agg2_kernel(
    const f16* __restrict__ h2p, const float* __restrict__ as2,
    const float* __restrict__ ad2, const int* __restrict__ rowptr,
    const int* __restrict__ csr, const float* __restrict__ b2,
    float* __restrict__ out) {
  const int wid = (blockIdx.x * 256 + threadIdx.x) >> 6;
  const int lane = threadIdx.x & 63;
  if (wid >= NN) return;
  const int lo = rowptr[wid], hi = rowptr[wid + 1];
  const int deg = hi - lo;
  const float advv = ad2[wid];
  float lkc = -3.4e38f;
  int sc = 0;
  if (lane < deg) {
    sc = csr[lo + lane];
    lkc = leaky02(as2[sc] + advv);
  }
  float m = lkc;
  for (int base = 64; base < deg; base += 64) {   // rare tail
    int e = base + lane;
    float xv = (e < deg) ? leaky02(as2[csr[lo + e]] + advv) : -3.4e38f;
    m = fmaxf(m, xv);
  }
#pragma unroll
  for (int off = 32; off >= 1; off >>= 1) m = fmaxf(m, __shfl_xor(m, off));
  const int j8 = lane >> 3, part8 = lane & 7;
  float sum = 0.f;
  float acc[8];
#pragma unroll
  for (int i = 0; i < 8; ++i) acc[i] = 0.f;
  for (int base = 0; base < deg; base += 64) {
    int e = base + lane;
    float p = 0.f;
    int s = 0;
    if (base == 0) {
      s = sc;
      if (lane < deg) p = __expf(lkc - m);
    } else if (e < deg) {
      s = csr[lo + e];
      p = __expf(leaky02(as2[s] + advv) - m);
    }
    sum += p;
    const int ng = (min(64, deg - base) + 7) >> 3;
    for (int g = 0; g < ng; ++g) {
      int sl = g * 8 + j8;
      int sj = __shfl(s, sl);
      float pj = __shfl(p, sl);
      f16x8 hv = *(const f16x8*)(h2p + (size_t)sj * 64 + part8 * 8);
#pragma unroll
      for (int i = 0; i < 8; ++i) acc[i] += pj * (float)hv[i];
    }
  }
#pragma unroll
  for (int off = 32; off >= 1; off >>= 1) sum += __shfl_xor(sum, off);
#pragma unroll
  for (int i = 0; i < 8; ++i) {
    acc[i] += __shfl_xor(acc[i], 8);
    acc[i] += __shfl_xor(acc[i], 16);
    acc[i] += __shfl_xor(acc[i], 32);
  }
  const float inv = 1.f / fmaxf(sum, 1e-16f);
  if (lane < 5) {   // j8 == 0, part8 == lane -> cols lane*8 .. lane*8+7
    float4 b0 = *(const float4*)(b2 + lane * 8);
    float4 b1 = *(const float4*)(b2 + lane * 8 + 4);
    float4 v0 = { acc[0] * inv + b0.x, acc[1] * inv + b0.y,
                  acc[2] * inv + b0.z, acc[3] * inv + b0.w };
    float4 v1 = { acc[4] * inv + b1.x, acc[5] * inv + b1.y,
                  acc[6] * inv + b1.z, acc[7] * inv + b1.w };
    *(float4*)(out + (size_t)wid * 40 + lane * 8) = v0;
    *(float4*)(out + (size_t)wid * 40 + lane * 8 + 4) = v1;
  }
}

extern "C" void kernel_launch(void* const* d_in, const int* in_sizes, int n_in,
                              void* d_out, int out_size, void* d_ws, size_t ws_size,
                              hipStream_t stream) {
  (void)in_sizes; (void)n_in; (void)out_size; (void)ws_size;
  const float* x = (const float*)d_in[0];
  const void* esrc = d_in[1];
  const void* edst = d_in[2];
  const float* W1 = (const float*)d_in[3];
  const float* att_s1 = (const float*)d_in[4];
  const float* att_d1 = (const float*)d_in[5];
  const float* W2 = (const float*)d_in[7];
  const float* att_s2 = (const float*)d_in[8];
  const float* att_d2 = (const float*)d_in[9];
  const float* b2 = (const float*)d_in[10];

  char* p = (char*)d_ws;
  auto alloc = [&](size_t bytes) {
    char* q = p;
    p += (bytes + 255) & ~(size_t)255;
    return q;
  };
  f16* h1 = (f16*)alloc((size_t)NN * 128 * 2);
  float* g1 = (float*)alloc((size_t)NN * 128 * 4);
  f16* h2p = (f16*)alloc((size_t)NN * 64 * 2);
  float* as1 = (float*)alloc((size_t)NN * 8 * 4);
  float* ad1 = (float*)alloc((size_t)NN * 8 * 4);
  float* as2 = (float*)alloc((size_t)NN * 4);
  float* ad2 = (float*)alloc((size_t)NN * 4);
  float* W2e = (float*)alloc((size_t)128 * 64 * 4);
  int* rowptr = (int*)alloc((size_t)(NN + 1) * 4);
  int* csr = (int*)alloc((size_t)NE * 4);
  unsigned int* bucketbuf = (unsigned int*)alloc((size_t)NE * 4);
  int* gbucket = (int*)alloc((size_t)NBKT * 4);
  int* bb = (int*)alloc((size_t)(NBKT + 1) * 4);
  int* bcur = (int*)alloc((size_t)NBKT * 4);
  int* flag = (int*)alloc(256);

  hipMemsetAsync(flag, 0, 4, stream);
  hipMemsetAsync(gbucket, 0, (size_t)NBKT * 4, stream);
  detect_kernel<<<4, 256, 0, stream>>>((const int*)esrc, flag);
  gemm1_kernel<<<512, 256, 0, stream>>>(x, W1, att_s1, att_d1, h1, as1, ad1);
  wprep_kernel<<<1, 256, 0, stream>>>(W2, att_s2, att_d2, W2e);
  bucketcnt_kernel<<<256, 256, 0, stream>>>(edst, flag, gbucket);
  bucketscan_kernel<<<1, 512, 0, stream>>>(gbucket, bb, bcur);
  partition_kernel<<<P2BLKS, 256, 0, stream>>>(esrc, edst, flag, bcur, bucketbuf);
  build_kernel<<<NBKT, 256, 0, stream>>>(bucketbuf, bb, rowptr, csr);
  agg1_kernel<<<25000, 256, 0, stream>>>(h1, as1, ad1, rowptr, csr, g1);
  gemm2_kernel<<<3125, 256, 0, stream>>>(g1, W2e, h2p, as2, ad2);
  agg2_kernel<<<25000, 256, 0, stream>>>(h2p, as2, ad2, rowptr, csr, b2, (float*)d_out);
}

// Round 10
// 317.529 us; speedup vs baseline: 1.6783x; 1.6783x over previous
//
#include <hip/hip_runtime.h>
#include <cstdint>
#include <cstddef>

#define NN 100000
#define NE 1600000
#define NH 8
#define NC 40
#define NBKT 391            // ceil(NN / 256)
#define CHUNK 8192
#define P2BLKS ((NE + CHUNK - 1) / CHUNK)

typedef _Float16 f16;
typedef f16 f16x2 __attribute__((ext_vector_type(2)));
typedef f16 f16x4 __attribute__((ext_vector_type(4)));
typedef f16 f16x8 __attribute__((ext_vector_type(8)));
typedef float f32x4 __attribute__((ext_vector_type(4)));

static __device__ __forceinline__ float leaky02(float x) {
  return x >= 0.f ? x : 0.2f * x;
}

// Detect whether edge arrays are int64 (odd int32 halves all zero) or int32.
__global__ void detect_kernel(const int* __restrict__ e, int* __restrict__ flag) {
  int i = blockIdx.x * blockDim.x + threadIdx.x;
  if (i < 1024) {
    if (e[2 * i + 1] != 0) atomicExch(flag, 1);
  }
}

static __device__ __forceinline__ int edge_at(const void* p, int is32, int i) {
  return is32 ? ((const int*)p)[i] : (int)((const long long*)p)[i];
}

// ------- layer-1 projection: h1 = x @ W1 (128x128), f16 out, fused att dots -
__global__ __launch_bounds__(256) void gemm1_kernel(
    const float* __restrict__ x, const float* __restrict__ W1,
    const float* __restrict__ att_src, const float* __restrict__ att_dst,
    f16* __restrict__ h1, float* __restrict__ as1, float* __restrict__ ad1) {
  __shared__ float wsm[128 * 128];   // [k][c]
  __shared__ float xs[16][136];
  for (int i = threadIdx.x; i < 128 * 32; i += 256)
    ((float4*)wsm)[i] = ((const float4*)W1)[i];
  const int r = threadIdx.x >> 4;      // row within tile (0..15)
  const int i16 = threadIdx.x & 15;    // column group
  const int ca = i16 * 4, cb = 64 + i16 * 4;
  const float4 asA = *(const float4*)(att_src + ca);
  const float4 asB = *(const float4*)(att_src + cb);
  const float4 adA = *(const float4*)(att_dst + ca);
  const float4 adB = *(const float4*)(att_dst + cb);
  const int hA = i16 >> 2, hB = 4 + (i16 >> 2);
  const int nt = (NN + 15) / 16;
  for (int tile = blockIdx.x; tile < nt; tile += gridDim.x) {
    const int row0 = tile * 16;
    __syncthreads();
    for (int t = threadIdx.x; t < 16 * 32; t += 256) {
      int rr = t >> 5, c4 = t & 31;
      int row = row0 + rr;
      float4 v = make_float4(0.f, 0.f, 0.f, 0.f);
      if (row < NN) v = ((const float4*)(x + (size_t)row * 128))[c4];
      *(float4*)&xs[rr][c4 * 4] = v;
    }
    __syncthreads();
    float4 accA = make_float4(0.f, 0.f, 0.f, 0.f);
    float4 accB = make_float4(0.f, 0.f, 0.f, 0.f);
#pragma unroll 8
    for (int k = 0; k < 128; ++k) {
      float xv = xs[r][k];
      float4 wa = *(const float4*)&wsm[k * 128 + ca];
      float4 wb = *(const float4*)&wsm[k * 128 + cb];
      accA.x += xv * wa.x; accA.y += xv * wa.y;
      accA.z += xv * wa.z; accA.w += xv * wa.w;
      accB.x += xv * wb.x; accB.y += xv * wb.y;
      accB.z += xv * wb.z; accB.w += xv * wb.w;
    }
    float psA = accA.x * asA.x + accA.y * asA.y + accA.z * asA.z + accA.w * asA.w;
    float psB = accB.x * asB.x + accB.y * asB.y + accB.z * asB.z + accB.w * asB.w;
    float pdA = accA.x * adA.x + accA.y * adA.y + accA.z * adA.z + accA.w * adA.w;
    float pdB = accB.x * adB.x + accB.y * adB.y + accB.z * adB.z + accB.w * adB.w;
    psA += __shfl_xor(psA, 1); psA += __shfl_xor(psA, 2);
    psB += __shfl_xor(psB, 1); psB += __shfl_xor(psB, 2);
    pdA += __shfl_xor(pdA, 1); pdA += __shfl_xor(pdA, 2);
    pdB += __shfl_xor(pdB, 1); pdB += __shfl_xor(pdB, 2);
    const int row = row0 + r;
    if (row < NN) {
      f16x4 oa = { (f16)accA.x, (f16)accA.y, (f16)accA.z, (f16)accA.w };
      f16x4 ob = { (f16)accB.x, (f16)accB.y, (f16)accB.z, (f16)accB.w };
      *(f16x4*)(h1 + (size_t)row * 128 + ca) = oa;
      *(f16x4*)(h1 + (size_t)row * 128 + cb) = ob;
      if ((i16 & 3) == 0) {
        as1[row * 8 + hA] = psA;
        as1[row * 8 + hB] = psB;
        ad1[row * 8 + hA] = pdA;
        ad1[row * 8 + hB] = pdB;
      }
    }
  }
}

// ---------------- CSR build: bucketed counting sort ----------------
__global__ __launch_bounds__(256) void bucketcnt_kernel(
    const void* __restrict__ dst, const int* __restrict__ flag,
    int* __restrict__ gbucket) {
  __shared__ int h[NBKT];
  const int t = threadIdx.x;
  for (int i = t; i < NBKT; i += 256) h[i] = 0;
  __syncthreads();
  const int is32 = *flag;
  int i = blockIdx.x * 256 + t;
  const int st = gridDim.x * 256;
  for (; i < NE; i += st) atomicAdd(&h[edge_at(dst, is32, i) >> 8], 1);
  __syncthreads();
  for (int b = t; b < NBKT; b += 256)
    if (h[b]) atomicAdd(&gbucket[b], h[b]);
}

__global__ __launch_bounds__(512) void bucketscan_kernel(
    const int* __restrict__ gbucket, int* __restrict__ bb,
    int* __restrict__ bcur) {
  __shared__ int wsum[8];
  const int t = threadIdx.x;
  const int lane = t & 63, w = t >> 6;
  int v = (t < NBKT) ? gbucket[t] : 0;
  int sc = v;
#pragma unroll
  for (int off = 1; off < 64; off <<= 1) {
    int o = __shfl_up(sc, off);
    if (lane >= off) sc += o;
  }
  if (lane == 63) wsum[w] = sc;
  __syncthreads();
  if (t < 8) {
    int ws = wsum[t];
#pragma unroll
    for (int off = 1; off < 8; off <<= 1) {
      int o = __shfl_up(ws, off);
      if (t >= off) ws += o;
    }
    wsum[t] = ws;
  }
  __syncthreads();
  if (w > 0) sc += wsum[w - 1];
  if (t < NBKT) {
    int ex = sc - v;
    bb[t] = ex;
    bcur[t] = ex;
  }
  if (t == NBKT - 1) bb[NBKT] = sc;   // == NE
}

__global__ __launch_bounds__(256) void partition_kernel(
    const void* __restrict__ src, const void* __restrict__ dst,
    const int* __restrict__ flag, int* __restrict__ bcur,
    unsigned int* __restrict__ bucketbuf) {
  __shared__ int h[NBKT];
  __shared__ int gb[NBKT];
  const int t = threadIdx.x;
  const int is32 = *flag;
  const int lo = blockIdx.x * CHUNK;
  const int hi = min(lo + CHUNK, NE);
  for (int i = t; i < NBKT; i += 256) h[i] = 0;
  __syncthreads();
  for (int i = lo + t; i < hi; i += 256)
    atomicAdd(&h[edge_at(dst, is32, i) >> 8], 1);
  __syncthreads();
  for (int b = t; b < NBKT; b += 256)
    gb[b] = h[b] ? atomicAdd(&bcur[b], h[b]) : 0;
  __syncthreads();
  for (int i = t; i < NBKT; i += 256) h[i] = 0;   // reuse as local cursor
  __syncthreads();
  for (int i = lo + t; i < hi; i += 256) {
    int d = edge_at(dst, is32, i);
    int b = d >> 8;
    int s = atomicAdd(&h[b], 1);
    bucketbuf[gb[b] + s] =
        ((unsigned)(d & 255) << 17) | (unsigned)edge_at(src, is32, i);
  }
}

__global__ __launch_bounds__(256) void build_kernel(
    const unsigned int* __restrict__ bucketbuf, const int* __restrict__ bb,
    int* __restrict__ rowptr, int* __restrict__ csr) {
  __shared__ int cnt[256];
  __shared__ int cur[256];
  __shared__ int wsum[4];
  const int k = blockIdx.x;
  const int t = threadIdx.x;
  const int node0 = k << 8;
  const int lo = bb[k], hi = bb[k + 1];
  cnt[t] = 0;
  __syncthreads();
  for (int i = lo + t; i < hi; i += 256)
    atomicAdd(&cnt[bucketbuf[i] >> 17], 1);
  __syncthreads();
  const int lane = t & 63, w = t >> 6;
  const int v = cnt[t];
  int sc = v;
#pragma unroll
  for (int off = 1; off < 64; off <<= 1) {
    int o = __shfl_up(sc, off);
    if (lane >= off) sc += o;
  }
  if (lane == 63) wsum[w] = sc;
  __syncthreads();
  if (t < 4) {
    int ws = wsum[t];
#pragma unroll
    for (int off = 1; off < 4; off <<= 1) {
      int o = __shfl_up(ws, off);
      if (t >= off) ws += o;
    }
    wsum[t] = ws;
  }
  __syncthreads();
  if (w > 0) sc += wsum[w - 1];
  const int ex = lo + sc - v;
  const int node = node0 + t;
  if (node < NN) rowptr[node] = ex;
  if (node == NN - 1) rowptr[NN] = NE;
  cur[t] = ex;
  __syncthreads();
  for (int i = lo + t; i < hi; i += 256) {
    unsigned e = bucketbuf[i];
    int pos = atomicAdd(&cur[e >> 17], 1);
    csr[pos] = (int)(e & 0x1FFFF);
  }
}

// ---- prep: W2p = MFMA-fragment-packed [s][t][lane][e] f16 of W2e[128][64] --
// W2e cols: 0..39 = W2, 40 = W2@att_src2, 41 = W2@att_dst2, 42..63 = 0.
// k-mapping (consistent with A-side): k = 32*s + (lane>>4)*8 + e, c = 16*t + (lane&15).
__global__ __launch_bounds__(256) void wprep_kernel(
    const float* __restrict__ W2, const float* __restrict__ as2v,
    const float* __restrict__ ad2v, f16* __restrict__ W2p) {
  for (int i = threadIdx.x; i < 8192; i += 256) {
    const int e = i & 7, lane = (i >> 3) & 63, t = (i >> 9) & 3, s = (i >> 11) & 3;
    const int k = 32 * s + ((lane >> 4) << 3) + e;
    const int c = 16 * t + (lane & 15);
    float v = 0.f;
    if (c < 40) {
      v = W2[k * 40 + c];
    } else if (c == 40 || c == 41) {
      const float* a = (c == 40) ? as2v : ad2v;
      float sacc = 0.f;
#pragma unroll 8
      for (int j = 0; j < 40; ++j) sacc += W2[k * 40 + j] * a[j];
      v = sacc;
    }
    W2p[i] = (f16)v;
  }
}

// --- layer-1 aggregate + softmax + ELU; g1 (f16) ---
// stats: lane = j*8+hd, first 4 batches cached in regs; PV: lane = q*16+part.
__global__ __launch_bounds__(256) void agg1_kernel(
    const f16* __restrict__ h1, const float* __restrict__ as1,
    const float* __restrict__ ad1, const int* __restrict__ rowptr,
    const int* __restrict__ csr, f16* __restrict__ g1) {
  const int wid = (blockIdx.x * 256 + threadIdx.x) >> 6;
  const int lane = threadIdx.x & 63;
  if (wid >= NN) return;
  const int lo = rowptr[wid], hi = rowptr[wid + 1];
  const int deg = hi - lo;
  const int j = lane >> 3, hd = lane & 7;
  const float advv = ad1[wid * 8 + hd];
  // cached stats for first 32 edges (covers ~all of Poisson-16)
  float lk0 = -3.4e38f, lk1 = -3.4e38f, lk2 = -3.4e38f, lk3 = -3.4e38f;
  int s0 = 0, s1 = 0, s2 = 0, s3 = 0;
  if (j < deg)      { s0 = csr[lo + j];      lk0 = leaky02(as1[(size_t)s0 * 8 + hd] + advv); }
  if (8 + j < deg)  { s1 = csr[lo + 8 + j];  lk1 = leaky02(as1[(size_t)s1 * 8 + hd] + advv); }
  if (16 + j < deg) { s2 = csr[lo + 16 + j]; lk2 = leaky02(as1[(size_t)s2 * 8 + hd] + advv); }
  if (24 + j < deg) { s3 = csr[lo + 24 + j]; lk3 = leaky02(as1[(size_t)s3 * 8 + hd] + advv); }
  float m = fmaxf(fmaxf(lk0, lk1), fmaxf(lk2, lk3));
  for (int base = 32; base < deg; base += 8) {   // rare tail
    int e = base + j;
    float xv = (e < deg) ? leaky02(as1[(size_t)csr[lo + e] * 8 + hd] + advv)
                         : -3.4e38f;
    m = fmaxf(m, xv);
  }
  m = fmaxf(m, __shfl_xor(m, 8));
  m = fmaxf(m, __shfl_xor(m, 16));
  m = fmaxf(m, __shfl_xor(m, 32));
  const int q = lane >> 4;          // PV edge sub-slot (0..3)
  const int part = lane & 15;       // 8-feature block
  float sum = 0.f;
  float acc[8];
#pragma unroll
  for (int i = 0; i < 8; ++i) acc[i] = 0.f;
  for (int base = 0; base < deg; base += 8) {
    int e = base + j;
    float p = 0.f;
    int s = 0;
    if (base == 0)       { s = s0; if (e < deg) p = __expf(lk0 - m); }
    else if (base == 8)  { s = s1; if (e < deg) p = __expf(lk1 - m); }
    else if (base == 16) { s = s2; if (e < deg) p = __expf(lk2 - m); }
    else if (base == 24) { s = s3; if (e < deg) p = __expf(lk3 - m); }
    else if (e < deg) {
      s = csr[lo + e];
      p = __expf(leaky02(as1[(size_t)s * 8 + hd] + advv) - m);
    }
    sum += p;
    int sja = __shfl(s, q * 8);
    float pja = __shfl(p, q * 8 + (part >> 1));
    int sjb = __shfl(s, (4 + q) * 8);
    float pjb = __shfl(p, (4 + q) * 8 + (part >> 1));
    f16x8 hva = *(const f16x8*)(h1 + (size_t)sja * 128 + part * 8);
    f16x8 hvb = *(const f16x8*)(h1 + (size_t)sjb * 128 + part * 8);
#pragma unroll
    for (int i = 0; i < 8; ++i) acc[i] += pja * (float)hva[i];
#pragma unroll
    for (int i = 0; i < 8; ++i) acc[i] += pjb * (float)hvb[i];
  }
  sum += __shfl_xor(sum, 8);
  sum += __shfl_xor(sum, 16);
  sum += __shfl_xor(sum, 32);
#pragma unroll
  for (int i = 0; i < 8; ++i) {
    acc[i] += __shfl_xor(acc[i], 16);
    acc[i] += __shfl_xor(acc[i], 32);
  }
  float sden = __shfl(sum, part >> 1);
  float inv = 1.f / fmaxf(sden, 1e-16f);
  if (lane < 16) {
    f16x8 ov;
#pragma unroll
    for (int i = 0; i < 8; ++i) {
      float v = acc[i] * inv;
      v = v > 0.f ? v : (__expf(v) - 1.f);
      ov[i] = (f16)v;
    }
    *(f16x8*)(g1 + (size_t)wid * 128 + part * 8) = ov;
  }
}

// ------- layer-2 projection via MFMA: h2p = g1 @ W2e (64 cols incl logits) --
// wave = 16 rows x 64 cols, K=128: 4 A-loads (f16x8 from row-major g1),
// 16 B-loads (packed W2p, L1-hot), 16 x mfma_f32_16x16x32_f16.
__global__ __launch_bounds__(256) void gemm2_kernel(
    const f16* __restrict__ g1, const f16* __restrict__ W2p,
    f16* __restrict__ h2p, float* __restrict__ as2, float* __restrict__ ad2) {
  const int lane = threadIdx.x & 63;
  const int wid = (blockIdx.x * 256 + threadIdx.x) >> 6;
  if (wid >= NN / 16) return;
  const int row0 = wid * 16;
  const int rsub = lane & 15;
  const int kg = lane >> 4;
  const f16* ap = g1 + (size_t)(row0 + rsub) * 128 + kg * 8;
  f16x8 a0 = *(const f16x8*)(ap);
  f16x8 a1 = *(const f16x8*)(ap + 32);
  f16x8 a2 = *(const f16x8*)(ap + 64);
  f16x8 a3 = *(const f16x8*)(ap + 96);
  const f16x8* bp = (const f16x8*)W2p;
  f32x4 acc[4];
  const f32x4 z4 = { 0.f, 0.f, 0.f, 0.f };
#pragma unroll
  for (int t = 0; t < 4; ++t) acc[t] = z4;
#pragma unroll
  for (int t = 0; t < 4; ++t) {
    acc[t] = __builtin_amdgcn_mfma_f32_16x16x32_f16(a0, bp[(0 * 4 + t) * 64 + lane], acc[t], 0, 0, 0);
    acc[t] = __builtin_amdgcn_mfma_f32_16x16x32_f16(a1, bp[(1 * 4 + t) * 64 + lane], acc[t], 0, 0, 0);
    acc[t] = __builtin_amdgcn_mfma_f32_16x16x32_f16(a2, bp[(2 * 4 + t) * 64 + lane], acc[t], 0, 0, 0);
    acc[t] = __builtin_amdgcn_mfma_f32_16x16x32_f16(a3, bp[(3 * 4 + t) * 64 + lane], acc[t], 0, 0, 0);
  }
  // C/D layout: col = lane&15 (+16t), row = (lane>>4)*4 + reg
  const int r0 = row0 + kg * 4;
#pragma unroll
  for (int t = 0; t < 4; ++t) {
    const int col = t * 16 + rsub;
    const bool live = col < 40;
#pragma unroll
    for (int r = 0; r < 4; ++r)
      h2p[(size_t)(r0 + r) * 64 + col] = live ? (f16)acc[t][r] : (f16)0.f;
  }
  if (rsub == 8) {          // col 40: src logits
#pragma unroll
    for (int r = 0; r < 4; ++r) as2[r0 + r] = acc[2][r];
  } else if (rsub == 9) {   // col 41: dst logits
#pragma unroll
    for (int r = 0; r < 4; ++r) ad2[r0 + r] = acc[2][r];
  }
}

// ---------------- layer-2 aggregate + softmax -> d_out ----------------
// stats: lane = edge offset (first 64 cached); PV: lane = j*8+part8, f16x8.
__global__ __launch_bounds__(256) void agg2_kernel(
    const f16* __restrict__ h2p, const float* __restrict__ as2,
    const float* __restrict__ ad2, const int* __restrict__ rowptr,
    const int* __restrict__ csr, const float* __restrict__ b2,
    float* __restrict__ out) {
  const int wid = (blockIdx.x * 256 + threadIdx.x) >> 6;
  const int lane = threadIdx.x & 63;
  if (wid >= NN) return;
  const int lo = rowptr[wid], hi = rowptr[wid + 1];
  const int deg = hi - lo;
  const float advv = ad2[wid];
  float lkc = -3.4e38f;
  int sc = 0;
  if (lane < deg) {
    sc = csr[lo + lane];
    lkc = leaky02(as2[sc] + advv);
  }
  float m = lkc;
  for (int base = 64; base < deg; base += 64) {   // rare tail
    int e = base + lane;
    float xv = (e < deg) ? leaky02(as2[csr[lo + e]] + advv) : -3.4e38f;
    m = fmaxf(m, xv);
  }
#pragma unroll
  for (int off = 32; off >= 1; off >>= 1) m = fmaxf(m, __shfl_xor(m, off));
  const int j8 = lane >> 3, part8 = lane & 7;
  float sum = 0.f;
  float acc[8];
#pragma unroll
  for (int i = 0; i < 8; ++i) acc[i] = 0.f;
  for (int base = 0; base < deg; base += 64) {
    int e = base + lane;
    float p = 0.f;
    int s = 0;
    if (base == 0) {
      s = sc;
      if (lane < deg) p = __expf(lkc - m);
    } else if (e < deg) {
      s = csr[lo + e];
      p = __expf(leaky02(as2[s] + advv) - m);
    }
    sum += p;
    const int ng = (min(64, deg - base) + 7) >> 3;
    for (int g = 0; g < ng; ++g) {
      int sl = g * 8 + j8;
      int sj = __shfl(s, sl);
      float pj = __shfl(p, sl);
      f16x8 hv = *(const f16x8*)(h2p + (size_t)sj * 64 + part8 * 8);
#pragma unroll
      for (int i = 0; i < 8; ++i) acc[i] += pj * (float)hv[i];
    }
  }
#pragma unroll
  for (int off = 32; off >= 1; off >>= 1) sum += __shfl_xor(sum, off);
#pragma unroll
  for (int i = 0; i < 8; ++i) {
    acc[i] += __shfl_xor(acc[i], 8);
    acc[i] += __shfl_xor(acc[i], 16);
    acc[i] += __shfl_xor(acc[i], 32);
  }
  const float inv = 1.f / fmaxf(sum, 1e-16f);
  if (lane < 5) {   // j8 == 0, part8 == lane -> cols lane*8 .. lane*8+7
    float4 b0 = *(const float4*)(b2 + lane * 8);
    float4 b1 = *(const float4*)(b2 + lane * 8 + 4);
    float4 v0 = { acc[0] * inv + b0.x, acc[1] * inv + b0.y,
                  acc[2] * inv + b0.z, acc[3] * inv + b0.w };
    float4 v1 = { acc[4] * inv + b1.x, acc[5] * inv + b1.y,
                  acc[6] * inv + b1.z, acc[7] * inv + b1.w };
    *(float4*)(out + (size_t)wid * 40 + lane * 8) = v0;
    *(float4*)(out + (size_t)wid * 40 + lane * 8 + 4) = v1;
  }
}

extern "C" void kernel_launch(void* const* d_in, const int* in_sizes, int n_in,
                              void* d_out, int out_size, void* d_ws, size_t ws_size,
                              hipStream_t stream) {
  (void)in_sizes; (void)n_in; (void)out_size; (void)ws_size;
  const float* x = (const float*)d_in[0];
  const void* esrc = d_in[1];
  const void* edst = d_in[2];
  const float* W1 = (const float*)d_in[3];
  const float* att_s1 = (const float*)d_in[4];
  const float* att_d1 = (const float*)d_in[5];
  const float* W2 = (const float*)d_in[7];
  const float* att_s2 = (const float*)d_in[8];
  const float* att_d2 = (const float*)d_in[9];
  const float* b2 = (const float*)d_in[10];

  char* p = (char*)d_ws;
  auto alloc = [&](size_t bytes) {
    char* q = p;
    p += (bytes + 255) & ~(size_t)255;
    return q;
  };
  f16* h1 = (f16*)alloc((size_t)NN * 128 * 2);
  f16* g1 = (f16*)alloc((size_t)NN * 128 * 2);
  f16* h2p = (f16*)alloc((size_t)NN * 64 * 2);
  float* as1 = (float*)alloc((size_t)NN * 8 * 4);
  float* ad1 = (float*)alloc((size_t)NN * 8 * 4);
  float* as2 = (float*)alloc((size_t)NN * 4);
  float* ad2 = (float*)alloc((size_t)NN * 4);
  f16* W2p = (f16*)alloc((size_t)8192 * 2);
  int* rowptr = (int*)alloc((size_t)(NN + 1) * 4);
  int* csr = (int*)alloc((size_t)NE * 4);
  unsigned int* bucketbuf = (unsigned int*)alloc((size_t)NE * 4);
  int* gbucket = (int*)alloc((size_t)NBKT * 4);
  int* bb = (int*)alloc((size_t)(NBKT + 1) * 4);
  int* bcur = (int*)alloc((size_t)NBKT * 4);
  int* flag = (int*)alloc(256);

  hipMemsetAsync(flag, 0, 4, stream);
  hipMemsetAsync(gbucket, 0, (size_t)NBKT * 4, stream);
  detect_kernel<<<4, 256, 0, stream>>>((const int*)esrc, flag);
  gemm1_kernel<<<512, 256, 0, stream>>>(x, W1, att_s1, att_d1, h1, as1, ad1);
  wprep_kernel<<<1, 256, 0, stream>>>(W2, att_s2, att_d2, W2p);
  bucketcnt_kernel<<<256, 256, 0, stream>>>(edst, flag, gbucket);
  bucketscan_kernel<<<1, 512, 0, stream>>>(gbucket, bb, bcur);
  partition_kernel<<<P2BLKS, 256, 0, stream>>>(esrc, edst, flag, bcur, bucketbuf);
  build_kernel<<<NBKT, 256, 0, stream>>>(bucketbuf, bb, rowptr, csr);
  agg1_kernel<<<25000, 256, 0, stream>>>(h1, as1, ad1, rowptr, csr, g1);
  gemm2_kernel<<<1563, 256, 0, stream>>>(g1, W2p, h2p, as2, ad2);
  agg2_kernel<<<25000, 256, 0, stream>>>(h2p, as2, ad2, rowptr, csr, b2, (float*)d_out);
}

// Round 12
// 288.001 us; speedup vs baseline: 1.8504x; 1.1025x over previous
//
#include <hip/hip_runtime.h>
#include <cstdint>
#include <cstddef>

#define NN 100000
#define NE 1600000
#define NH 8
#define NC 40
#define NBKT 391            // ceil(NN / 256)
#define CHUNK 8192
#define P2BLKS ((NE + CHUNK - 1) / CHUNK)

typedef _Float16 f16;
typedef f16 f16x2 __attribute__((ext_vector_type(2)));
typedef f16 f16x4 __attribute__((ext_vector_type(4)));
typedef f16 f16x8 __attribute__((ext_vector_type(8)));
typedef float f32x4 __attribute__((ext_vector_type(4)));

static __device__ __forceinline__ float leaky02(float x) {
  return x >= 0.f ? x : 0.2f * x;
}

// Detect whether edge arrays are int64 (odd int32 halves all zero) or int32.
__global__ void detect_kernel(const int* __restrict__ e, int* __restrict__ flag) {
  int i = blockIdx.x * blockDim.x + threadIdx.x;
  if (i < 1024) {
    if (e[2 * i + 1] != 0) atomicExch(flag, 1);
  }
}

static __device__ __forceinline__ int edge_at(const void* p, int is32, int i) {
  return is32 ? ((const int*)p)[i] : (int)((const long long*)p)[i];
}

// ---- prep: w1b2[k][col] = sum_f W1[k][h*16+f] * att[h*16+f]  (fused logits) -
// col 0..7: h=col, att=att_src ; col 8..15: h=col-8, att=att_dst.
__global__ __launch_bounds__(128) void w1b2_kernel(
    const float* __restrict__ W1, const float* __restrict__ att_src,
    const float* __restrict__ att_dst, float* __restrict__ w1b2) {
  const int k = threadIdx.x;
#pragma unroll
  for (int col = 0; col < 16; ++col) {
    const int h = col & 7;
    const float* av = (col < 8) ? att_src : att_dst;
    float v = 0.f;
#pragma unroll
    for (int f = 0; f < 16; ++f)
      v += W1[k * 128 + h * 16 + f] * av[h * 16 + f];
    w1b2[k * 16 + col] = v;
  }
}

// ------- layer-1 projection via MFMA: h1 = x @ W1 (128x128) + att dots ------
// wave = 16 rows. W1 packed as f16 fragments in LDS (32 KB); att dots via
// w1b2 = W1 @ B2 (128x16), B2 block-diagonal from att_src/att_dst.
__global__ __launch_bounds__(256) void gemm1_kernel(
    const float* __restrict__ x, const float* __restrict__ W1,
    const float* __restrict__ w1b2, f16* __restrict__ h1,
    float* __restrict__ as1, float* __restrict__ ad1) {
  __shared__ f16 wp[16384];    // [kt][ct][lane][e]
  __shared__ f16 wp2[2048];    // [kt][lane][e]
  const int t = threadIdx.x;
  for (int i = t; i < 16384; i += 256) {
    const int e = i & 7, ln = (i >> 3) & 63, ct = (i >> 9) & 7, kt = i >> 12;
    const int k = kt * 32 + ((ln >> 4) << 3) + e;
    const int c = ct * 16 + (ln & 15);
    wp[i] = (f16)W1[k * 128 + c];
  }
  for (int i = t; i < 2048; i += 256) {
    const int e = i & 7, ln = (i >> 3) & 63, kt = i >> 9;
    const int k = kt * 32 + ((ln >> 4) << 3) + e;
    const int col = ln & 15;
    wp2[i] = (f16)w1b2[k * 16 + col];
  }
  __syncthreads();
  const int lane = t & 63;
  const int rsub = lane & 15, kg = lane >> 4;
  const int wid = (blockIdx.x * 256 + t) >> 6;
  if (wid >= NN / 16) return;
  const int row0 = wid * 16;
  const float* ap = x + (size_t)(row0 + rsub) * 128 + kg * 8;
  f16x8 a[4];
#pragma unroll
  for (int kt = 0; kt < 4; ++kt) {
    float4 v0 = *(const float4*)(ap + kt * 32);
    float4 v1 = *(const float4*)(ap + kt * 32 + 4);
    f16x8 av = { (f16)v0.x, (f16)v0.y, (f16)v0.z, (f16)v0.w,
                 (f16)v1.x, (f16)v1.y, (f16)v1.z, (f16)v1.w };
    a[kt] = av;
  }
  const f16x8* bp = (const f16x8*)wp;
  const f16x8* bp2 = (const f16x8*)wp2;
  const f32x4 z4 = { 0.f, 0.f, 0.f, 0.f };
  f32x4 acc[8];
#pragma unroll
  for (int ct = 0; ct < 8; ++ct) acc[ct] = z4;
  f32x4 acc2 = z4;
#pragma unroll
  for (int kt = 0; kt < 4; ++kt) {
#pragma unroll
    for (int ct = 0; ct < 8; ++ct)
      acc[ct] = __builtin_amdgcn_mfma_f32_16x16x32_f16(
          a[kt], bp[(kt * 8 + ct) * 64 + lane], acc[ct], 0, 0, 0);
    acc2 = __builtin_amdgcn_mfma_f32_16x16x32_f16(
        a[kt], bp2[kt * 64 + lane], acc2, 0, 0, 0);
  }
  // C/D: col = ct*16 + rsub, row = kg*4 + r
  const int r0 = row0 + kg * 4;
#pragma unroll
  for (int ct = 0; ct < 8; ++ct) {
#pragma unroll
    for (int r = 0; r < 4; ++r)
      h1[(size_t)(r0 + r) * 128 + ct * 16 + rsub] = (f16)acc[ct][r];
  }
#pragma unroll
  for (int r = 0; r < 4; ++r) {
    if (rsub < 8) as1[(r0 + r) * 8 + rsub] = acc2[r];
    else          ad1[(r0 + r) * 8 + rsub - 8] = acc2[r];
  }
}

// ---------------- CSR build: bucketed counting sort ----------------
__global__ __launch_bounds__(256) void bucketcnt_kernel(
    const void* __restrict__ dst, const int* __restrict__ flag,
    int* __restrict__ gbucket) {
  __shared__ int h[NBKT];
  const int t = threadIdx.x;
  for (int i = t; i < NBKT; i += 256) h[i] = 0;
  __syncthreads();
  const int is32 = *flag;
  int i = blockIdx.x * 256 + t;
  const int st = gridDim.x * 256;
  for (; i < NE; i += st) atomicAdd(&h[edge_at(dst, is32, i) >> 8], 1);
  __syncthreads();
  for (int b = t; b < NBKT; b += 256)
    if (h[b]) atomicAdd(&gbucket[b], h[b]);
}

__global__ __launch_bounds__(512) void bucketscan_kernel(
    const int* __restrict__ gbucket, int* __restrict__ bb,
    int* __restrict__ bcur) {
  __shared__ int wsum[8];
  const int t = threadIdx.x;
  const int lane = t & 63, w = t >> 6;
  int v = (t < NBKT) ? gbucket[t] : 0;
  int sc = v;
#pragma unroll
  for (int off = 1; off < 64; off <<= 1) {
    int o = __shfl_up(sc, off);
    if (lane >= off) sc += o;
  }
  if (lane == 63) wsum[w] = sc;
  __syncthreads();
  if (t < 8) {
    int ws = wsum[t];
#pragma unroll
    for (int off = 1; off < 8; off <<= 1) {
      int o = __shfl_up(ws, off);
      if (t >= off) ws += o;
    }
    wsum[t] = ws;
  }
  __syncthreads();
  if (w > 0) sc += wsum[w - 1];
  if (t < NBKT) {
    int ex = sc - v;
    bb[t] = ex;
    bcur[t] = ex;
  }
  if (t == NBKT - 1) bb[NBKT] = sc;   // == NE
}

__global__ __launch_bounds__(256) void partition_kernel(
    const void* __restrict__ src, const void* __restrict__ dst,
    const int* __restrict__ flag, int* __restrict__ bcur,
    unsigned int* __restrict__ bucketbuf) {
  __shared__ int h[NBKT];
  __shared__ int gb[NBKT];
  const int t = threadIdx.x;
  const int is32 = *flag;
  const int lo = blockIdx.x * CHUNK;
  const int hi = min(lo + CHUNK, NE);
  for (int i = t; i < NBKT; i += 256) h[i] = 0;
  __syncthreads();
  for (int i = lo + t; i < hi; i += 256)
    atomicAdd(&h[edge_at(dst, is32, i) >> 8], 1);
  __syncthreads();
  for (int b = t; b < NBKT; b += 256)
    gb[b] = h[b] ? atomicAdd(&bcur[b], h[b]) : 0;
  __syncthreads();
  for (int i = t; i < NBKT; i += 256) h[i] = 0;   // reuse as local cursor
  __syncthreads();
  for (int i = lo + t; i < hi; i += 256) {
    int d = edge_at(dst, is32, i);
    int b = d >> 8;
    int s = atomicAdd(&h[b], 1);
    bucketbuf[gb[b] + s] =
        ((unsigned)(d & 255) << 17) | (unsigned)edge_at(src, is32, i);
  }
}

__global__ __launch_bounds__(256) void build_kernel(
    const unsigned int* __restrict__ bucketbuf, const int* __restrict__ bb,
    int* __restrict__ rowptr, int* __restrict__ csr) {
  __shared__ int cnt[256];
  __shared__ int cur[256];
  __shared__ int wsum[4];
  const int k = blockIdx.x;
  const int t = threadIdx.x;
  const int node0 = k << 8;
  const int lo = bb[k], hi = bb[k + 1];
  cnt[t] = 0;
  __syncthreads();
  for (int i = lo + t; i < hi; i += 256)
    atomicAdd(&cnt[bucketbuf[i] >> 17], 1);
  __syncthreads();
  const int lane = t & 63, w = t >> 6;
  const int v = cnt[t];
  int sc = v;
#pragma unroll
  for (int off = 1; off < 64; off <<= 1) {
    int o = __shfl_up(sc, off);
    if (lane >= off) sc += o;
  }
  if (lane == 63) wsum[w] = sc;
  __syncthreads();
  if (t < 4) {
    int ws = wsum[t];
#pragma unroll
    for (int off = 1; off < 4; off <<= 1) {
      int o = __shfl_up(ws, off);
      if (t >= off) ws += o;
    }
    wsum[t] = ws;
  }
  __syncthreads();
  if (w > 0) sc += wsum[w - 1];
  const int ex = lo + sc - v;
  const int node = node0 + t;
  if (node < NN) rowptr[node] = ex;
  if (node == NN - 1) rowptr[NN] = NE;
  cur[t] = ex;
  __syncthreads();
  for (int i = lo + t; i < hi; i += 256) {
    unsigned e = bucketbuf[i];
    int pos = atomicAdd(&cur[e >> 17], 1);
    csr[pos] = (int)(e & 0x1FFFF);
  }
}

// ---- prep: W2p = MFMA-fragment-packed [s][t][lane][e] f16 of W2e[128][64] --
__global__ __launch_bounds__(256) void wprep_kernel(
    const float* __restrict__ W2, const float* __restrict__ as2v,
    const float* __restrict__ ad2v, f16* __restrict__ W2p) {
  for (int i = threadIdx.x; i < 8192; i += 256) {
    const int e = i & 7, lane = (i >> 3) & 63, t = (i >> 9) & 3, s = (i >> 11) & 3;
    const int k = 32 * s + ((lane >> 4) << 3) + e;
    const int c = 16 * t + (lane & 15);
    float v = 0.f;
    if (c < 40) {
      v = W2[k * 40 + c];
    } else if (c == 40 || c == 41) {
      const float* a = (c == 40) ? as2v : ad2v;
      float sacc = 0.f;
#pragma unroll 8
      for (int j = 0; j < 40; ++j) sacc += W2[k * 40 + j] * a[j];
      v = sacc;
    }
    W2p[i] = (f16)v;
  }
}

// --- layer-1 aggregate + softmax + ELU; g1 (f16) ---
// stats: lane = j*8+hd, first 4 batches cached in regs; PV: lane = q*16+part.
__global__ __launch_bounds__(256) void agg1_kernel(
    const f16* __restrict__ h1, const float* __restrict__ as1,
    const float* __restrict__ ad1, const int* __restrict__ rowptr,
    const int* __restrict__ csr, f16* __restrict__ g1) {
  const int wid = (blockIdx.x * 256 + threadIdx.x) >> 6;
  const int lane = threadIdx.x & 63;
  if (wid >= NN) return;
  const int lo = rowptr[wid], hi = rowptr[wid + 1];
  const int deg = hi - lo;
  const int j = lane >> 3, hd = lane & 7;
  const float advv = ad1[wid * 8 + hd];
  float lk0 = -3.4e38f, lk1 = -3.4e38f, lk2 = -3.4e38f, lk3 = -3.4e38f;
  int s0 = 0, s1 = 0, s2 = 0, s3 = 0;
  if (j < deg)      { s0 = csr[lo + j];      lk0 = leaky02(as1[(size_t)s0 * 8 + hd] + advv); }
  if (8 + j < deg)  { s1 = csr[lo + 8 + j];  lk1 = leaky02(as1[(size_t)s1 * 8 + hd] + advv); }
  if (16 + j < deg) { s2 = csr[lo + 16 + j]; lk2 = leaky02(as1[(size_t)s2 * 8 + hd] + advv); }
  if (24 + j < deg) { s3 = csr[lo + 24 + j]; lk3 = leaky02(as1[(size_t)s3 * 8 + hd] + advv); }
  float m = fmaxf(fmaxf(lk0, lk1), fmaxf(lk2, lk3));
  for (int base = 32; base < deg; base += 8) {   // rare tail
    int e = base + j;
    float xv = (e < deg) ? leaky02(as1[(size_t)csr[lo + e] * 8 + hd] + advv)
                         : -3.4e38f;
    m = fmaxf(m, xv);
  }
  m = fmaxf(m, __shfl_xor(m, 8));
  m = fmaxf(m, __shfl_xor(m, 16));
  m = fmaxf(m, __shfl_xor(m, 32));
  const int q = lane >> 4;          // PV edge sub-slot (0..3)
  const int part = lane & 15;       // 8-feature block
  float sum = 0.f;
  float acc[8];
#pragma unroll
  for (int i = 0; i < 8; ++i) acc[i] = 0.f;
  for (int base = 0; base < deg; base += 8) {
    int e = base + j;
    float p = 0.f;
    int s = 0;
    if (base == 0)       { s = s0; if (e < deg) p = __expf(lk0 - m); }
    else if (base == 8)  { s = s1; if (e < deg) p = __expf(lk1 - m); }
    else if (base == 16) { s = s2; if (e < deg) p = __expf(lk2 - m); }
    else if (base == 24) { s = s3; if (e < deg) p = __expf(lk3 - m); }
    else if (e < deg) {
      s = csr[lo + e];
      p = __expf(leaky02(as1[(size_t)s * 8 + hd] + advv) - m);
    }
    sum += p;
    int sja = __shfl(s, q * 8);
    float pja = __shfl(p, q * 8 + (part >> 1));
    int sjb = __shfl(s, (4 + q) * 8);
    float pjb = __shfl(p, (4 + q) * 8 + (part >> 1));
    f16x8 hva = *(const f16x8*)(h1 + (size_t)sja * 128 + part * 8);
    f16x8 hvb = *(const f16x8*)(h1 + (size_t)sjb * 128 + part * 8);
#pragma unroll
    for (int i = 0; i < 8; ++i) acc[i] += pja * (float)hva[i];
#pragma unroll
    for (int i = 0; i < 8; ++i) acc[i] += pjb * (float)hvb[i];
  }
  sum += __shfl_xor(sum, 8);
  sum += __shfl_xor(sum, 16);
  sum += __shfl_xor(sum, 32);
#pragma unroll
  for (int i = 0; i < 8; ++i) {
    acc[i] += __shfl_xor(acc[i], 16);
    acc[i] += __shfl_xor(acc[i], 32);
  }
  float sden = __shfl(sum, part >> 1);
  float inv = 1.f / fmaxf(sden, 1e-16f);
  if (lane < 16) {
    f16x8 ov;
#pragma unroll
    for (int i = 0; i < 8; ++i) {
      float v = acc[i] * inv;
      v = v > 0.f ? v : (__expf(v) - 1.f);
      ov[i] = (f16)v;
    }
    *(f16x8*)(g1 + (size_t)wid * 128 + part * 8) = ov;
  }
}

// ------- layer-2 projection via MFMA: h2p = g1 @ W2e (64 cols incl logits) --
__global__ __launch_bounds__(256) void gemm2_kernel(
    const f16* __restrict__ g1, const f16* __restrict__ W2p,
    f16* __restrict__ h2p, float* __restrict__ as2, float* __restrict__ ad2) {
  const int lane = threadIdx.x & 63;
  const int wid = (blockIdx.x * 256 + threadIdx.x) >> 6;
  if (wid >= NN / 16) return;
  const int row0 = wid * 16;
  const int rsub = lane & 15;
  const int kg = lane >> 4;
  const f16* ap = g1 + (size_t)(row0 + rsub) * 128 + kg * 8;
  f16x8 a0 = *(const f16x8*)(ap);
  f16x8 a1 = *(const f16x8*)(ap + 32);
  f16x8 a2 = *(const f16x8*)(ap + 64);
  f16x8 a3 = *(const f16x8*)(ap + 96);
  const f16x8* bp = (const f16x8*)W2p;
  f32x4 acc[4];
  const f32x4 z4 = { 0.f, 0.f, 0.f, 0.f };
#pragma unroll
  for (int t = 0; t < 4; ++t) acc[t] = z4;
#pragma unroll
  for (int t = 0; t < 4; ++t) {
    acc[t] = __builtin_amdgcn_mfma_f32_16x16x32_f16(a0, bp[(0 * 4 + t) * 64 + lane], acc[t], 0, 0, 0);
    acc[t] = __builtin_amdgcn_mfma_f32_16x16x32_f16(a1, bp[(1 * 4 + t) * 64 + lane], acc[t], 0, 0, 0);
    acc[t] = __builtin_amdgcn_mfma_f32_16x16x32_f16(a2, bp[(2 * 4 + t) * 64 + lane], acc[t], 0, 0, 0);
    acc[t] = __builtin_amdgcn_mfma_f32_16x16x32_f16(a3, bp[(3 * 4 + t) * 64 + lane], acc[t], 0, 0, 0);
  }
  const int r0 = row0 + kg * 4;
#pragma unroll
  for (int t = 0; t < 4; ++t) {
    const int col = t * 16 + rsub;
    const bool live = col < 40;
#pragma unroll
    for (int r = 0; r < 4; ++r)
      h2p[(size_t)(r0 + r) * 64 + col] = live ? (f16)acc[t][r] : (f16)0.f;
  }
  if (rsub == 8) {          // col 40: src logits
#pragma unroll
    for (int r = 0; r < 4; ++r) as2[r0 + r] = acc[2][r];
  } else if (rsub == 9) {   // col 41: dst logits
#pragma unroll
    for (int r = 0; r < 4; ++r) ad2[r0 + r] = acc[2][r];
  }
}

// ---------------- layer-2 aggregate + softmax -> d_out ----------------
__global__ __launch_bounds__(256) void agg2_kernel(
    const f16* __restrict__ h2p, const float* __restrict__ as2,
    const float* __restrict__ ad2, const int* __restrict__ rowptr,
    const int* __restrict__ csr, const float* __restrict__ b2,
    float* __restrict__ out) {
  const int wid = (blockIdx.x * 256 + threadIdx.x) >> 6;
  const int lane = threadIdx.x & 63;
  if (wid >= NN) return;
  const int lo = rowptr[wid], hi = rowptr[wid + 1];
  const int deg = hi - lo;
  const float advv = ad2[wid];
  float lkc = -3.4e38f;
  int sc = 0;
  if (lane < deg) {
    sc = csr[lo + lane];
    lkc = leaky02(as2[sc] + advv);
  }
  float m = lkc;
  for (int base = 64; base < deg; base += 64) {   // rare tail
    int e = base + lane;
    float xv = (e < deg) ? leaky02(as2[csr[lo + e]] + advv) : -3.4e38f;
    m = fmaxf(m, xv);
  }
#pragma unroll
  for (int off = 32; off >= 1; off >>= 1) m = fmaxf(m, __shfl_xor(m, off));
  const int j8 = lane >> 3, part8 = lane & 7;
  float sum = 0.f;
  float acc[8];
#pragma unroll
  for (int i = 0; i < 8; ++i) acc[i] = 0.f;
  for (int base = 0; base < deg; base += 64) {
    int e = base + lane;
    float p = 0.f;
    int s = 0;
    if (base == 0) {
      s = sc;
      if (lane < deg) p = __expf(lkc - m);
    } else if (e < deg) {
      s = csr[lo + e];
      p = __expf(leaky02(as2[s] + advv) - m);
    }
    sum += p;
    const int ng = (min(64, deg - base) + 7) >> 3;
    for (int g = 0; g < ng; ++g) {
      int sl = g * 8 + j8;
      int sj = __shfl(s, sl);
      float pj = __shfl(p, sl);
      f16x8 hv = *(const f16x8*)(h2p + (size_t)sj * 64 + part8 * 8);
#pragma unroll
      for (int i = 0; i < 8; ++i) acc[i] += pj * (float)hv[i];
    }
  }
#pragma unroll
  for (int off = 32; off >= 1; off >>= 1) sum += __shfl_xor(sum, off);
#pragma unroll
  for (int i = 0; i < 8; ++i) {
    acc[i] += __shfl_xor(acc[i], 8);
    acc[i] += __shfl_xor(acc[i], 16);
    acc[i] += __shfl_xor(acc[i], 32);
  }
  const float inv = 1.f / fmaxf(sum, 1e-16f);
  if (lane < 5) {   // j8 == 0, part8 == lane -> cols lane*8 .. lane*8+7
    float4 b0 = *(const float4*)(b2 + lane * 8);
    float4 b1 = *(const float4*)(b2 + lane * 8 + 4);
    float4 v0 = { acc[0] * inv + b0.x, acc[1] * inv + b0.y,
                  acc[2] * inv + b0.z, acc[3] * inv + b0.w };
    float4 v1 = { acc[4] * inv + b1.x, acc[5] * inv + b1.y,
                  acc[6] * inv + b1.z, acc[7] * inv + b1.w };
    *(float4*)(out + (size_t)wid * 40 + lane * 8) = v0;
    *(float4*)(out + (size_t)wid * 40 + lane * 8 + 4) = v1;
  }
}

extern "C" void kernel_launch(void* const* d_in, const int* in_sizes, int n_in,
                              void* d_out, int out_size, void* d_ws, size_t ws_size,
                              hipStream_t stream) {
  (void)in_sizes; (void)n_in; (void)out_size; (void)ws_size;
  const float* x = (const float*)d_in[0];
  const void* esrc = d_in[1];
  const void* edst = d_in[2];
  const float* W1 = (const float*)d_in[3];
  const float* att_s1 = (const float*)d_in[4];
  const float* att_d1 = (const float*)d_in[5];
  const float* W2 = (const float*)d_in[7];
  const float* att_s2 = (const float*)d_in[8];
  const float* att_d2 = (const float*)d_in[9];
  const float* b2 = (const float*)d_in[10];

  char* p = (char*)d_ws;
  auto alloc = [&](size_t bytes) {
    char* q = p;
    p += (bytes + 255) & ~(size_t)255;
    return q;
  };
  f16* h1 = (f16*)alloc((size_t)NN * 128 * 2);
  f16* g1 = (f16*)alloc((size_t)NN * 128 * 2);
  f16* h2p = (f16*)alloc((size_t)NN * 64 * 2);
  float* as1 = (float*)alloc((size_t)NN * 8 * 4);
  float* ad1 = (float*)alloc((size_t)NN * 8 * 4);
  float* as2 = (float*)alloc((size_t)NN * 4);
  float* ad2 = (float*)alloc((size_t)NN * 4);
  f16* W2p = (f16*)alloc((size_t)8192 * 2);
  float* w1b2 = (float*)alloc((size_t)128 * 16 * 4);
  int* rowptr = (int*)alloc((size_t)(NN + 1) * 4);
  int* csr = (int*)alloc((size_t)NE * 4);
  unsigned int* bucketbuf = (unsigned int*)alloc((size_t)NE * 4);
  int* gbucket = (int*)alloc((size_t)NBKT * 4);
  int* bb = (int*)alloc((size_t)(NBKT + 1) * 4);
  int* bcur = (int*)alloc((size_t)NBKT * 4);
  int* flag = (int*)alloc(256);

  hipMemsetAsync(flag, 0, 4, stream);
  hipMemsetAsync(gbucket, 0, (size_t)NBKT * 4, stream);
  detect_kernel<<<4, 256, 0, stream>>>((const int*)esrc, flag);
  w1b2_kernel<<<1, 128, 0, stream>>>(W1, att_s1, att_d1, w1b2);
  gemm1_kernel<<<1563, 256, 0, stream>>>(x, W1, w1b2, h1, as1, ad1);
  wprep_kernel<<<1, 256, 0, stream>>>(W2, att_s2, att_d2, W2p);
  bucketcnt_kernel<<<256, 256, 0, stream>>>(edst, flag, gbucket);
  bucketscan_kernel<<<1, 512, 0, stream>>>(gbucket, bb, bcur);
  partition_kernel<<<P2BLKS, 256, 0, stream>>>(esrc, edst, flag, bcur, bucketbuf);
  build_kernel<<<NBKT, 256, 0, stream>>>(bucketbuf, bb, rowptr, csr);
  agg1_kernel<<<25000, 256, 0, stream>>>(h1, as1, ad1, rowptr, csr, g1);
  gemm2_kernel<<<1563, 256, 0, stream>>>(g1, W2p, h2p, as2, ad2);
  agg2_kernel<<<25000, 256, 0, stream>>>(h2p, as2, ad2, rowptr, csr, b2, (float*)d_out);
}